// Round 2
// baseline (372.566 us; speedup 1.0000x reference)
//
#include <hip/hip_runtime.h>
#include <stdint.h>

// DTI WLS fit -> FA, with exact replication of the reference's SymEig noise:
//   noise = 1e-6 * jax.random.normal(key(42), (100,100,100,3,3), f32)
// JAX threefry (partitionable path): 32-bit draw for element idx = second
// output of threefry2x32(key=(0,42), counter=(idx>>32, idx&0xffffffff)).
// normal = sqrt(2) * erfinv(u*2 + lo), lo = nextafter(-1,0) = -0.99999994,
// u = bitcast((bits>>9)|0x3f800000) - 1, clamped with max(lo, .).
// erfinv = XLA's Giles polynomial (exact constants).
//
// This revision: block-cooperative LDS staging of the dwi reads.
//   - per block: 256 voxels x 64 grads x 4B = 64 KiB, contiguous in global
//   - staged via global_load_lds_dwordx4 (wave-linear dest, coalesced 1 KiB/instr)
//   - LDS read swizzle slot ^= (voxel&7) kills the 256B-stride 32-way bank
//     conflict; swizzle applied on the GLOBAL source address (involution),
//     LDS destination stays linear as global_load_lds requires (m104/m173).

__device__ __forceinline__ unsigned tf_rotl(unsigned x, int r) {
  return (x << r) | (x >> (32 - r));
}

// Threefry-2x32, 20 rounds, key (0, 42); returns SECOND output word.
__device__ __forceinline__ unsigned threefry_second(unsigned x0, unsigned x1) {
  const unsigned k0 = 0u, k1 = 42u;
  const unsigned k2 = 0x1BD11BDAu ^ k0 ^ k1;
  x0 += k0; x1 += k1;
#define TF_ROUND(r) { x0 += x1; x1 = tf_rotl(x1, r); x1 ^= x0; }
  TF_ROUND(13) TF_ROUND(15) TF_ROUND(26) TF_ROUND(6)
  x0 += k1; x1 += k2 + 1u;
  TF_ROUND(17) TF_ROUND(29) TF_ROUND(16) TF_ROUND(24)
  x0 += k2; x1 += k0 + 2u;
  TF_ROUND(13) TF_ROUND(15) TF_ROUND(26) TF_ROUND(6)
  x0 += k0; x1 += k1 + 3u;
  TF_ROUND(17) TF_ROUND(29) TF_ROUND(16) TF_ROUND(24)
  x0 += k1; x1 += k2 + 4u;
  TF_ROUND(13) TF_ROUND(15) TF_ROUND(26) TF_ROUND(6)
  x0 += k2; x1 += k0 + 5u;
#undef TF_ROUND
  (void)x0;
  return x1;
}

// XLA ErfInv32 (Giles), exact constants.
__device__ __forceinline__ float erfinv_xla(float x) {
  float w = -__logf(fmaf(-x, x, 1.0f));
  float p;
  if (w < 5.0f) {
    w = w - 2.5f;
    p = 2.81022636e-08f;
    p = fmaf(p, w, 3.43273939e-07f);
    p = fmaf(p, w, -3.5233877e-06f);
    p = fmaf(p, w, -4.39150654e-06f);
    p = fmaf(p, w, 0.00021858087f);
    p = fmaf(p, w, -0.00125372503f);
    p = fmaf(p, w, -0.00417768164f);
    p = fmaf(p, w, 0.246640727f);
    p = fmaf(p, w, 1.50140941f);
  } else {
    w = __builtin_sqrtf(w) - 3.0f;
    p = -0.000200214257f;
    p = fmaf(p, w, 0.000100950558f);
    p = fmaf(p, w, 0.00134934322f);
    p = fmaf(p, w, -0.00367342844f);
    p = fmaf(p, w, 0.00573950773f);
    p = fmaf(p, w, -0.0076224613f);
    p = fmaf(p, w, 0.00943887047f);
    p = fmaf(p, w, 1.00167406f);
    p = fmaf(p, w, 2.83297682f);
  }
  return p * x;
}

__device__ __forceinline__ float jax_normal_at(unsigned idx) {
  unsigned bits = threefry_second(0u, idx);   // counter hi = 0 (idx < 2^32)
  float f = __uint_as_float((bits >> 9) | 0x3F800000u);  // [1,2)
  float u = f - 1.0f;                                    // [0,1)
  const float lo = -0.99999994f;                          // nextafter(-1,0)
  float val = fmaf(u, 2.0f, lo);                          // (hi-lo) rounds to 2.0f
  val = fmaxf(lo, val);
  return 1.41421356237f * erfinv_xla(val);                // sqrt(2) in f32
}

#define NG 64
#define VPB 256  // voxels per block (== blockDim.x)

typedef __attribute__((address_space(1))) const void gvoid_t;
typedef __attribute__((address_space(3))) void lvoid_t;

__global__ __launch_bounds__(256) void fa_kernel(
    const float* __restrict__ dwi,
    const float* __restrict__ mask,
    const float* __restrict__ W,     // [7,64], rows 0..5 used
    const float* __restrict__ mdp,   // scalar min_diffusivity
    float* __restrict__ out,
    int nvox)
{
  // 256 voxels x 64 grads x 4B = 64 KiB -> 2 blocks/CU (LDS-capped)
  __shared__ float4 smem[VPB * NG / 4];   // 4096 float4 slots

  const int t    = threadIdx.x;
  const int wid  = t >> 6;
  const int lane = t & 63;

  const size_t blockBaseF = (size_t)blockIdx.x * VPB * NG;       // float index
  const float* gbase = dwi + blockBaseF;
  // number of float4 slots in this block's region backed by real data
  const size_t validSlots = ((size_t)nvox * NG - blockBaseF) >> 2;

  // ---- stage 64 KiB global -> LDS, coalesced, source-side XOR swizzle ----
  // LDS dest is linear (HW: wave-uniform base + lane*16). We want
  // LDS[slot] = global[slot ^ ((slot>>4)&7)]  (involution), so the read-side
  // XOR recovers voxel rows conflict-free.
#pragma unroll
  for (int i = 0; i < 16; ++i) {
    const int baseSlot = wid * 1024 + i * 64;   // wave-uniform
    const int slot = baseSlot + lane;
    int srcSlot = slot ^ ((slot >> 4) & 7);     // per-lane swizzled source
    if ((size_t)srcSlot >= validSlots) srcSlot = 0;  // tail clamp (data unused)
    __builtin_amdgcn_global_load_lds(
        (gvoid_t*)(gbase + (size_t)srcSlot * 4),
        (lvoid_t*)(smem + baseSlot),
        16, 0, 0);
  }
  __syncthreads();   // emits s_waitcnt vmcnt(0) + barrier

  const int v = blockIdx.x * VPB + t;
  if (v >= nvox) return;

  const float md = mdp[0];

  // ---- matvec: fit[i] = sum_j W[i][j] * log(max(dwi[v][j], md)) ----
  // voxel row lives at slots [t*16, t*16+16), stored swizzled by (t&7).
  const int rb = t << 4;
  const int sw = t & 7;
  float f0 = 0.f, f1 = 0.f, f2 = 0.f, f3 = 0.f, f4 = 0.f, f5 = 0.f;
#pragma unroll
  for (int j4 = 0; j4 < 16; ++j4) {
    float4 d = smem[rb + (j4 ^ sw)];   // lanes 0..7 cover all 32 banks
    float xs[4];
    xs[0] = __logf(fmaxf(d.x, md));
    xs[1] = __logf(fmaxf(d.y, md));
    xs[2] = __logf(fmaxf(d.z, md));
    xs[3] = __logf(fmaxf(d.w, md));
#pragma unroll
    for (int k = 0; k < 4; ++k) {
      int j = j4 * 4 + k;
      float x = xs[k];
      f0 = fmaf(W[0 * NG + j], x, f0);
      f1 = fmaf(W[1 * NG + j], x, f1);
      f2 = fmaf(W[2 * NG + j], x, f2);
      f3 = fmaf(W[3 * NG + j], x, f3);
      f4 = fmaf(W[4 * NG + j], x, f4);
      f5 = fmaf(W[5 * NG + j], x, f5);
    }
  }

  // ---- tensor (LT_INDICES): [[f0,f1,f3],[f1,f2,f4],[f3,f4,f5]] + noise, symmetrized ----
  unsigned base = 9u * (unsigned)v;
  float z[9];
#pragma unroll
  for (int e = 0; e < 9; ++e) z[e] = jax_normal_at(base + (unsigned)e);

  const float eps = 1e-6f;
  float a00 = f0 + eps * z[0];
  float a11 = f2 + eps * z[4];
  float a22 = f5 + eps * z[8];
  float a01 = ((f1 + eps * z[1]) + (f1 + eps * z[3])) * 0.5f;
  float a02 = ((f3 + eps * z[2]) + (f3 + eps * z[6])) * 0.5f;
  float a12 = ((f4 + eps * z[5]) + (f4 + eps * z[7])) * 0.5f;

  // ---- closed-form symmetric 3x3 eigenvalues (trigonometric method) ----
  float q = (a00 + a11 + a22) * (1.0f / 3.0f);
  float aa = a00 - q, bb = a11 - q, cc = a22 - q;
  float p2 = aa * aa + bb * bb + cc * cc +
             2.0f * (a01 * a01 + a02 * a02 + a12 * a12);
  float pp = __builtin_sqrtf(p2 * (1.0f / 6.0f));
  float invp = (pp > 0.0f) ? (1.0f / pp) : 0.0f;
  float b00 = aa * invp, b11 = bb * invp, b22 = cc * invp;
  float b01 = a01 * invp, b02 = a02 * invp, b12 = a12 * invp;
  float detB = b00 * (b11 * b22 - b12 * b12)
             - b01 * (b01 * b22 - b12 * b02)
             + b02 * (b01 * b12 - b11 * b02);
  float r = 0.5f * detB;
  r = fminf(1.0f, fmaxf(-1.0f, r));
  float phi = acosf(r) * (1.0f / 3.0f);
  float l0 = q + 2.0f * pp * cosf(phi);
  float l2 = q + 2.0f * pp * cosf(phi + 2.0943951023931953f); // +2pi/3
  float l1 = 3.0f * q - l0 - l2;

  // ---- clamp, FA ----
  l0 = fmaxf(l0, md);
  l1 = fmaxf(l1, md);
  l2 = fmaxf(l2, md);
  float d01 = l0 - l1, d12 = l1 - l2, d20 = l2 - l0;
  float num = 0.5f * (d01 * d01 + d12 * d12 + d20 * d20);
  float den = l0 * l0 + l1 * l1 + l2 * l2;  // >= 3*md^2 > 0, all_zero impossible
  float fa = __builtin_sqrtf(num / den);

  out[v] = fa * mask[v];
}

extern "C" void kernel_launch(void* const* d_in, const int* in_sizes, int n_in,
                              void* d_out, int out_size, void* d_ws, size_t ws_size,
                              hipStream_t stream) {
  const float* dwi  = (const float*)d_in[0];
  const float* mask = (const float*)d_in[1];
  const float* W    = (const float*)d_in[2];
  const float* mdp  = (const float*)d_in[3];
  float* out = (float*)d_out;
  int nvox = in_sizes[0] / NG;  // 1,000,000
  int grid = (nvox + VPB - 1) / VPB;
  hipLaunchKernelGGL(fa_kernel, dim3(grid), dim3(VPB), 0, stream,
                     dwi, mask, W, mdp, out, nvox);
}

// Round 3
// 357.212 us; speedup vs baseline: 1.0430x; 1.0430x over previous
//
#include <hip/hip_runtime.h>
#include <stdint.h>

// DTI WLS fit -> FA, with exact replication of the reference's SymEig noise:
//   noise = 1e-6 * jax.random.normal(key(42), (100,100,100,3,3), f32)
// JAX threefry (partitionable path): 32-bit draw for element idx = second
// output of threefry2x32(key=(0,42), counter=(idx>>32, idx&0xffffffff)).
// normal = sqrt(2) * erfinv(u*2 + lo), lo = nextafter(-1,0) = -0.99999994.
// erfinv = XLA's Giles polynomial (exact constants).
//
// Round-3 structure (fixing round-2's 21.7% occupancy / exposed stage latency):
//   - chunked staging: 4 chunks x 16 grads, wave-private LDS regions,
//     double-buffered: LDS = 4 waves x 2 bufs x 4 KiB = 32 KiB  -> VGPR-capped
//     occupancy (16 waves/CU, ~50%) instead of LDS-capped (8 waves/CU).
//   - NO __syncthreads: each wave stages exactly its own 64 voxels; sync via
//     counted s_waitcnt vmcnt(N) (loads stay in flight across chunks, T4).
//   - noise z[9] (~900 pure-ALU insts) computed between stage-issue and first
//     consume -> fully hides HBM latency of the first two chunks.
//   - XOR swizzle for 4-slot rows: store slot = v*4 + (q ^ ((v>>1)&3)) via
//     pre-swizzled GLOBAL source (LDS dest stays linear per global_load_lds
//     contract); read lane*4 + (j ^ ((lane>>1)&3)) -> 8 distinct 16B positions
//     per 8 lanes = conflict-free minimum for wave64 ds_read_b128.

__device__ __forceinline__ unsigned tf_rotl(unsigned x, int r) {
  return (x << r) | (x >> (32 - r));
}

// Threefry-2x32, 20 rounds, key (0, 42); returns SECOND output word.
__device__ __forceinline__ unsigned threefry_second(unsigned x0, unsigned x1) {
  const unsigned k0 = 0u, k1 = 42u;
  const unsigned k2 = 0x1BD11BDAu ^ k0 ^ k1;
  x0 += k0; x1 += k1;
#define TF_ROUND(r) { x0 += x1; x1 = tf_rotl(x1, r); x1 ^= x0; }
  TF_ROUND(13) TF_ROUND(15) TF_ROUND(26) TF_ROUND(6)
  x0 += k1; x1 += k2 + 1u;
  TF_ROUND(17) TF_ROUND(29) TF_ROUND(16) TF_ROUND(24)
  x0 += k2; x1 += k0 + 2u;
  TF_ROUND(13) TF_ROUND(15) TF_ROUND(26) TF_ROUND(6)
  x0 += k0; x1 += k1 + 3u;
  TF_ROUND(17) TF_ROUND(29) TF_ROUND(16) TF_ROUND(24)
  x0 += k1; x1 += k2 + 4u;
  TF_ROUND(13) TF_ROUND(15) TF_ROUND(26) TF_ROUND(6)
  x0 += k2; x1 += k0 + 5u;
#undef TF_ROUND
  (void)x0;
  return x1;
}

// XLA ErfInv32 (Giles), exact constants.
__device__ __forceinline__ float erfinv_xla(float x) {
  float w = -__logf(fmaf(-x, x, 1.0f));
  float p;
  if (w < 5.0f) {
    w = w - 2.5f;
    p = 2.81022636e-08f;
    p = fmaf(p, w, 3.43273939e-07f);
    p = fmaf(p, w, -3.5233877e-06f);
    p = fmaf(p, w, -4.39150654e-06f);
    p = fmaf(p, w, 0.00021858087f);
    p = fmaf(p, w, -0.00125372503f);
    p = fmaf(p, w, -0.00417768164f);
    p = fmaf(p, w, 0.246640727f);
    p = fmaf(p, w, 1.50140941f);
  } else {
    w = __builtin_sqrtf(w) - 3.0f;
    p = -0.000200214257f;
    p = fmaf(p, w, 0.000100950558f);
    p = fmaf(p, w, 0.00134934322f);
    p = fmaf(p, w, -0.00367342844f);
    p = fmaf(p, w, 0.00573950773f);
    p = fmaf(p, w, -0.0076224613f);
    p = fmaf(p, w, 0.00943887047f);
    p = fmaf(p, w, 1.00167406f);
    p = fmaf(p, w, 2.83297682f);
  }
  return p * x;
}

__device__ __forceinline__ float jax_normal_at(unsigned idx) {
  unsigned bits = threefry_second(0u, idx);   // counter hi = 0 (idx < 2^32)
  float f = __uint_as_float((bits >> 9) | 0x3F800000u);  // [1,2)
  float u = f - 1.0f;                                    // [0,1)
  const float lo = -0.99999994f;                          // nextafter(-1,0)
  float val = fmaf(u, 2.0f, lo);                          // (hi-lo) rounds to 2.0f
  val = fmaxf(lo, val);
  return 1.41421356237f * erfinv_xla(val);                // sqrt(2) in f32
}

#define NG 64

typedef __attribute__((address_space(1))) const void gvoid_t;
typedef __attribute__((address_space(3))) void lvoid_t;

#define VMWAIT(n) asm volatile("s_waitcnt vmcnt(" #n ")" ::: "memory")
#define CLOB()    asm volatile("" ::: "memory")

__global__ __launch_bounds__(256, 4) void fa_kernel(
    const float* __restrict__ dwi,
    const float* __restrict__ mask,
    const float* __restrict__ W,     // [7,64], rows 0..5 used
    const float* __restrict__ mdp,   // scalar min_diffusivity
    float* __restrict__ out,
    int nvox)
{
  // [wave][buf][slot]: 4 x 2 x 256 float4 = 32 KiB
  __shared__ float4 smem[4][2][256];

  const int t    = threadIdx.x;
  const int wid  = t >> 6;
  const int lane = t & 63;
  const int v    = blockIdx.x * 256 + t;
  const size_t wvox    = (size_t)blockIdx.x * 256 + (size_t)(wid * 64);
  const size_t totalF4 = (size_t)nvox * (NG / 4);

  const float md = mdp[0];

  // ---- stage chunk c (grads [16c,16c+16)) of this wave's 64 voxels into buf b.
  // LDS dest linear (HW: uniform base + lane*16B); source pre-swizzled so that
  // LDS[v_local*4 + (q ^ ((v_local>>1)&3))] = G[(wvox+v_local)*16 + c*4 + q].
#define STAGE(c, b) do {                                                   \
    _Pragma("unroll")                                                      \
    for (int i = 0; i < 4; ++i) {                                          \
      int vl = i * 16 + (lane >> 2);                                       \
      int q  = (lane & 3) ^ ((vl >> 1) & 3);                               \
      size_t src = (wvox + (size_t)vl) * (NG / 4) + (c) * 4 + (size_t)q;   \
      if (src >= totalF4) src = 0;  /* tail clamp, data unused */          \
      __builtin_amdgcn_global_load_lds(                                    \
          (gvoid_t*)(dwi + src * 4),                                       \
          (lvoid_t*)(&smem[wid][(b)][i * 64]), 16, 0, 0);                  \
    }                                                                      \
    CLOB();                                                                \
  } while (0)

  float f0 = 0.f, f1 = 0.f, f2 = 0.f, f3 = 0.f, f4 = 0.f, f5 = 0.f;
  const int swz   = (lane >> 1) & 3;
  const int rbase = lane * 4;

  // ---- consume chunk c from buf b: 16 logs + 96 fma into f0..f5 ----
#define MATVEC(c, b) do {                                                  \
    _Pragma("unroll")                                                      \
    for (int j = 0; j < 4; ++j) {                                          \
      float4 d = smem[wid][(b)][rbase + (j ^ swz)];                        \
      float xs[4];                                                         \
      xs[0] = __logf(fmaxf(d.x, md));                                      \
      xs[1] = __logf(fmaxf(d.y, md));                                      \
      xs[2] = __logf(fmaxf(d.z, md));                                      \
      xs[3] = __logf(fmaxf(d.w, md));                                      \
      _Pragma("unroll")                                                    \
      for (int k = 0; k < 4; ++k) {                                        \
        int jg = (c) * 16 + j * 4 + k;                                     \
        float x = xs[k];                                                   \
        f0 = fmaf(W[0 * NG + jg], x, f0);                                  \
        f1 = fmaf(W[1 * NG + jg], x, f1);                                  \
        f2 = fmaf(W[2 * NG + jg], x, f2);                                  \
        f3 = fmaf(W[3 * NG + jg], x, f3);                                  \
        f4 = fmaf(W[4 * NG + jg], x, f4);                                  \
        f5 = fmaf(W[5 * NG + jg], x, f5);                                  \
      }                                                                    \
    }                                                                      \
  } while (0)

  // ---- issue first two chunks (8 loads in flight) ----
  STAGE(0, 0);
  STAGE(1, 1);

  // ---- noise z[9]: pure ALU (~900 insts), hides staging HBM latency ----
  unsigned base = 9u * (unsigned)v;
  float z[9];
#pragma unroll
  for (int e = 0; e < 9; ++e) z[e] = jax_normal_at(base + (unsigned)e);

  // ---- pipelined consume: counted vmcnt, never drain to 0 mid-loop ----
  VMWAIT(4);          // S0 landed (S1 may be in flight)
  MATVEC(0, 0);
  STAGE(2, 0);        // safe: chunk0 values already consumed into regs
  VMWAIT(4);          // S1 landed (S2 in flight)
  MATVEC(1, 1);
  STAGE(3, 1);
  float mv = mask[v < nvox ? v : 0];  // pinned between CLOBs, counted below
  CLOB();
  VMWAIT(5);          // S2 landed (S3 + mask in flight)
  MATVEC(2, 0);
  VMWAIT(1);          // S3 landed (mask may be in flight)
  MATVEC(3, 1);

  // ---- tensor (LT_INDICES): [[f0,f1,f3],[f1,f2,f4],[f3,f4,f5]] + noise, symmetrized ----
  const float eps = 1e-6f;
  float a00 = f0 + eps * z[0];
  float a11 = f2 + eps * z[4];
  float a22 = f5 + eps * z[8];
  float a01 = ((f1 + eps * z[1]) + (f1 + eps * z[3])) * 0.5f;
  float a02 = ((f3 + eps * z[2]) + (f3 + eps * z[6])) * 0.5f;
  float a12 = ((f4 + eps * z[5]) + (f4 + eps * z[7])) * 0.5f;

  // ---- closed-form symmetric 3x3 eigenvalues (trigonometric method) ----
  float q = (a00 + a11 + a22) * (1.0f / 3.0f);
  float aa = a00 - q, bb = a11 - q, cc = a22 - q;
  float p2 = aa * aa + bb * bb + cc * cc +
             2.0f * (a01 * a01 + a02 * a02 + a12 * a12);
  float pp = __builtin_sqrtf(p2 * (1.0f / 6.0f));
  float invp = (pp > 0.0f) ? (1.0f / pp) : 0.0f;
  float b00 = aa * invp, b11 = bb * invp, b22 = cc * invp;
  float b01 = a01 * invp, b02 = a02 * invp, b12 = a12 * invp;
  float detB = b00 * (b11 * b22 - b12 * b12)
             - b01 * (b01 * b22 - b12 * b02)
             + b02 * (b01 * b12 - b11 * b02);
  float r = 0.5f * detB;
  r = fminf(1.0f, fmaxf(-1.0f, r));
  float phi = acosf(r) * (1.0f / 3.0f);
  float l0 = q + 2.0f * pp * cosf(phi);
  float l2 = q + 2.0f * pp * cosf(phi + 2.0943951023931953f); // +2pi/3
  float l1 = 3.0f * q - l0 - l2;

  // ---- clamp, FA ----
  l0 = fmaxf(l0, md);
  l1 = fmaxf(l1, md);
  l2 = fmaxf(l2, md);
  float d01 = l0 - l1, d12 = l1 - l2, d20 = l2 - l0;
  float num = 0.5f * (d01 * d01 + d12 * d12 + d20 * d20);
  float den = l0 * l0 + l1 * l1 + l2 * l2;  // >= 3*md^2 > 0
  float fa = __builtin_sqrtf(num / den);

  if (v < nvox) out[v] = fa * mv;
}

extern "C" void kernel_launch(void* const* d_in, const int* in_sizes, int n_in,
                              void* d_out, int out_size, void* d_ws, size_t ws_size,
                              hipStream_t stream) {
  const float* dwi  = (const float*)d_in[0];
  const float* mask = (const float*)d_in[1];
  const float* W    = (const float*)d_in[2];
  const float* mdp  = (const float*)d_in[3];
  float* out = (float*)d_out;
  int nvox = in_sizes[0] / NG;  // 1,000,000
  int grid = (nvox + 255) / 256;
  hipLaunchKernelGGL(fa_kernel, dim3(grid), dim3(256), 0, stream,
                     dwi, mask, W, mdp, out, nvox);
}